// Round 6
// baseline (259.487 us; speedup 1.0000x reference)
//
#include <hip/hip_runtime.h>
#include <math.h>

// NoisyTopkRouter: B=8,S=4096,D=1024,E=64,k=2
// R6: barrier-free K-loop. fp16x3-emulated MFMA (32x32x16), verified R3-R5:
//   C = A_hi*B_hi + (A_hi*B_lo' + A_lo'*B_hi)/2048
// Pre-pass splits B (128x1024 fp32) once into ws as fp16 hi/lo in MFMA
// FRAGMENT order -> main-kernel B loads are coalesced 16B/lane, no LDS, no
// barrier, no per-block split VALU. Main: block = 32 tok, 128 thr = 2 waves,
// each wave owns K-half 512 with private LDS A staging (no __syncthreads in
// K-loop; wave-internal lgkm ordering). 2 barriers at end for split-K
// reduction via Cs overlay + verified epilogue.

#define DIM 1024
#define NEXP 64
#define LS 40               // A staging row stride in halves (80B)
#define CS 132              // Cs row stride in floats
#define LOSCALE 2048.0f
#define INV_LOSCALE (1.0f / 2048.0f)

using half4v   = __attribute__((ext_vector_type(4)))  _Float16;
using half8v   = __attribute__((ext_vector_type(8)))  _Float16;
using floatx16 = __attribute__((ext_vector_type(16))) float;

__device__ inline void split4(const float4 v, half4v& hi, half4v& lo) {
    _Float16 h0 = (_Float16)v.x, h1 = (_Float16)v.y,
             h2 = (_Float16)v.z, h3 = (_Float16)v.w;
    hi = (half4v){h0, h1, h2, h3};
    lo = (half4v){(_Float16)((v.x - (float)h0) * LOSCALE),
                  (_Float16)((v.y - (float)h1) * LOSCALE),
                  (_Float16)((v.z - (float)h2) * LOSCALE),
                  (_Float16)((v.w - (float)h3) * LOSCALE)};
}

__device__ inline half8v mk8(const half4v a, const half4v b) {
    return (half8v){a[0], a[1], a[2], a[3], b[0], b[1], b[2], b[3]};
}

#define MFMA32(a, b, c) __builtin_amdgcn_mfma_f32_32x32x16_f16((a), (b), (c), 0, 0, 0)

// ---- pre-pass: split W (Wl++Wn) into fp16 hi/lo in MFMA-fragment order ----
// frag layout: g = ((nc*64 + f)*64 + lane), f = k-16-chunk (0..63);
// element = W[e = nc*32 + (lane&31)][k = f*16 + (lane>>5)*8 .. +8]
__global__ __launch_bounds__(64)
void split_B(const float* __restrict__ Wl, const float* __restrict__ Wn,
             _Float16* __restrict__ bhi, _Float16* __restrict__ blo)
{
    const int g = blockIdx.x * 64 + threadIdx.x;    // 0..16383
    const int lane = g & 63;
    const int f    = (g >> 6) & 63;
    const int nc   = g >> 12;
    const int e = nc * 32 + (lane & 31);
    const int k = f * 16 + (lane >> 5) * 8;
    const float* W = ((e < NEXP) ? (Wl + (size_t)e * DIM)
                                 : (Wn + (size_t)(e - NEXP) * DIM)) + k;
    float4 v0 = *(const float4*)(W);
    float4 v1 = *(const float4*)(W + 4);
    half4v h0, l0, h1, l1;
    split4(v0, h0, l0);
    split4(v1, h1, l1);
    *(half8v*)(bhi + (size_t)g * 8) = mk8(h0, h1);
    *(half8v*)(blo + (size_t)g * 8) = mk8(l0, l1);
}

// ---- main kernel ----
__global__ __launch_bounds__(128, 2)
void router_main(const float* __restrict__ h, const _Float16* __restrict__ bhi,
                 const _Float16* __restrict__ blo, const float* __restrict__ bl,
                 const float* __restrict__ bn, const float* __restrict__ noise,
                 float* __restrict__ outR, float* __restrict__ outIx,
                 float* __restrict__ outF, int M)
{
    // union: per-wave A staging (2 waves x 2 buf x hi/lo x 32*LS = 20480 B)
    // then Cs[2][32][CS] floats (33792 B)
    __shared__ float smem[2 * 32 * CS];

    const int tid   = threadIdx.x;      // 0..127
    const int wv    = tid >> 6;         // K-half 0/1
    const int lane  = tid & 63;
    const int row31 = lane & 31;
    const int oct   = lane >> 5;
    const int tok0  = blockIdx.x * 32;
    const int kbase = wv * 512;

    _Float16* Abase = (_Float16*)smem + wv * 5120;  // 2 bufs x (hi1280+lo1280)

    // A global map: 2 lanes per row, 64B each
    const int arow = lane >> 1, acol = lane & 1;
    const float* hp = h + (size_t)(tok0 + arow) * DIM + kbase + acol * 16;
    const int sA = arow * LS + acol * 16;   // staging slot (halves), + q*4
    const int fA = row31 * LS + oct * 8;    // frag offset, + ks*16

    // B frag base: offset(nc,t,ks) = (nc*64 + (wv*16+t)*2 + ks)*512 + lane*8
    const _Float16* bhp = bhi + (size_t)lane * 8 + (size_t)(wv * 16) * 2 * 512;
    const _Float16* blp = blo + (size_t)lane * 8 + (size_t)(wv * 16) * 2 * 512;

    floatx16 acc1[4], acc2[4];
#pragma unroll
    for (int nc = 0; nc < 4; nc++)
#pragma unroll
        for (int i = 0; i < 16; i++) { acc1[nc][i] = 0.f; acc2[nc][i] = 0.f; }

    float4 av[4];
#pragma unroll
    for (int q = 0; q < 4; q++) av[q] = *(const float4*)(hp + q * 4);

    for (int t = 0; t < 16; t++) {
        // split+store A(t) into private buf[t&1] (regs loaded last iter)
        _Float16* Ahi = Abase + (t & 1) * 2560;
        _Float16* Alo = Ahi + 1280;
#pragma unroll
        for (int q = 0; q < 4; q++) {
            half4v hi, lo;
            split4(av[q], hi, lo);
            *(half4v*)(Ahi + sA + q * 4) = hi;
            *(half4v*)(Alo + sA + q * 4) = lo;
        }
        // frag-read A(t) (wave-internal lgkm ordering; no barrier)
        half8v aH[2], aL[2];
#pragma unroll
        for (int ks = 0; ks < 2; ks++) {
            aH[ks] = *(const half8v*)(Ahi + fA + ks * 16);
            aL[ks] = *(const half8v*)(Alo + fA + ks * 16);
        }
        // prefetch A(t+1)
        if (t < 15) {
#pragma unroll
            for (int q = 0; q < 4; q++)
                av[q] = *(const float4*)(hp + (t + 1) * 32 + q * 4);
        }
        // B loads (coalesced frag-order, L2-hot) + 24 MFMA
#pragma unroll
        for (int nc = 0; nc < 4; nc++) {
#pragma unroll
            for (int ks = 0; ks < 2; ks++) {
                const size_t off = (size_t)(nc * 64 + t * 2 + ks) * 512;
                half8v bH = *(const half8v*)(bhp + off);
                half8v bL = *(const half8v*)(blp + off);
                acc1[nc] = MFMA32(aH[ks], bH, acc1[nc]);
                acc2[nc] = MFMA32(aH[ks], bL, acc2[nc]);
                acc2[nc] = MFMA32(aL[ks], bH, acc2[nc]);
            }
        }
    }

    __syncthreads();   // both waves done with staging regions; Cs overlay safe

    // write partial C plane: col=lane&31, row=(i&3)+8*(i>>2)+4*oct (verified)
    float* Cs = smem + wv * (32 * CS);
#pragma unroll
    for (int nc = 0; nc < 4; nc++) {
#pragma unroll
        for (int i = 0; i < 16; i++) {
            int rowt = (i & 3) + 8 * (i >> 2) + 4 * oct;
            Cs[rowt * CS + nc * 32 + row31] = acc1[nc][i] + acc2[nc][i] * INV_LOSCALE;
        }
    }
    __syncthreads();

    // ---- epilogue: wave wv handles tokens wv*16..+15 (verified R1-R5 math) ----
    const float blv = bl[lane];
    const float bnv = bn[lane];
    const float* Cs0 = smem;
    const float* Cs1 = smem + 32 * CS;

    for (int i = 0; i < 16; i++) {
        const int t = wv * 16 + i;
        const int gt = tok0 + t;
        float xr = Cs0[t * CS + lane] + Cs1[t * CS + lane] + blv;
        float xf = Cs0[t * CS + 64 + lane] + Cs1[t * CS + 64 + lane] + bnv;
        float nz = noise[(size_t)gt * NEXP + lane];

        // softplus (matches jax.nn.softplus)
        float stdv = fmaxf(xf, 0.f) + log1pf(expf(-fabsf(xf)));
        float noisy = fmaf(nz, stdv, xr);

        // full softmax over 64 lanes
        float m = noisy;
#pragma unroll
        for (int o = 32; o > 0; o >>= 1) m = fmaxf(m, __shfl_xor(m, o, 64));
        float p = expf(noisy - m);
        float s = p;
#pragma unroll
        for (int o = 32; o > 0; o >>= 1) s += __shfl_xor(s, o, 64);
        float fullp = p / s;

        // argmax #1 (ties -> lowest index, matching lax.top_k)
        float v = noisy; int idx = lane;
#pragma unroll
        for (int o = 32; o > 0; o >>= 1) {
            float ov = __shfl_xor(v, o, 64);
            int   oi = __shfl_xor(idx, o, 64);
            if (ov > v || (ov == v && oi < idx)) { v = ov; idx = oi; }
        }
        const float v1 = v; const int i1 = idx;
        // argmax #2
        v = (lane == i1) ? -INFINITY : noisy; idx = lane;
#pragma unroll
        for (int o = 32; o > 0; o >>= 1) {
            float ov = __shfl_xor(v, o, 64);
            int   oi = __shfl_xor(idx, o, 64);
            if (ov > v || (ov == v && oi < idx)) { v = ov; idx = oi; }
        }
        const float v2 = v; const int i2 = idx;

        // sparse softmax over {i1,i2}
        float e2 = expf(v2 - v1);
        float den = 1.f + e2;
        float routep = (lane == i1) ? (1.f / den) : ((lane == i2) ? (e2 / den) : 0.f);

        outR[(size_t)gt * NEXP + lane] = routep;
        outF[(size_t)gt * NEXP + lane] = fullp;
        if (lane == 0) {
            outIx[(size_t)gt * 2 + 0] = (float)i1;
            outIx[(size_t)gt * 2 + 1] = (float)i2;
        }
    }
}

extern "C" void kernel_launch(void* const* d_in, const int* in_sizes, int n_in,
                              void* d_out, int out_size, void* d_ws, size_t ws_size,
                              hipStream_t stream) {
    const float* h     = (const float*)d_in[0];
    const float* Wl    = (const float*)d_in[1];
    const float* bl    = (const float*)d_in[2];
    const float* Wn    = (const float*)d_in[3];
    const float* bn    = (const float*)d_in[4];
    const float* noise = (const float*)d_in[5];
    float* out = (float*)d_out;

    const int M = in_sizes[0] / DIM;                 // 32768
    float* outR  = out;                              // [M,64]
    float* outIx = out + (size_t)M * NEXP;           // [M,2]
    float* outF  = outIx + (size_t)M * 2;            // [M,64]

    _Float16* bhi = (_Float16*)d_ws;                 // 128*1024 halves = 256 KB
    _Float16* blo = bhi + 128 * DIM;                 // +256 KB (ws >= 16MB, proven R4)

    split_B<<<256, 64, 0, stream>>>(Wl, Wn, bhi, blo);
    router_main<<<M / 32, 128, 0, stream>>>(h, bhi, blo, bl, bn, noise,
                                            outR, outIx, outF, M);
}